// Round 2
// baseline (10562.406 us; speedup 1.0000x reference)
//
#include <hip/hip_runtime.h>
#include <hip/hip_bf16.h>

#define EPS_GN 1e-5f
#define NEG_SLOPE 0.2f

static constexpr int  Bn   = 2;
static constexpr int  Cn   = 32;
static constexpr int  Dn   = 24;
static constexpr int  Hn   = 160;
static constexpr int  Wn   = 160;
static constexpr int  HWn  = Hn * Wn;              // 25600
static constexpr long DHWn = (long)Dn * HWn;       // 614400
static constexpr long NPIX = (long)Bn * Dn * HWn;  // 1228800
static constexpr int  GPIX = Bn * HWn;             // 51200 (pixels per GRU step per dir)

__device__ __forceinline__ float bf2f(__hip_bfloat16 v) { return __bfloat162float(v); }
__device__ __forceinline__ __hip_bfloat16 f2bf(float v) { return __float2bfloat16(v); }

// ---------------------------------------------------------------------------
// Transpose fp32 weight [O][IK] -> [IK][O] (input-major so the inner o-loop
// in conv kernels reads contiguous, wave-uniform addresses).
// ---------------------------------------------------------------------------
__global__ __launch_bounds__(256) void wtrans_kernel(
    const float* __restrict__ src, float* __restrict__ dst, int O, int IK)
{
    int i = blockIdx.x * 256 + threadIdx.x;
    if (i >= O * IK) return;
    int o = i / IK, ik = i - o * IK;
    dst[ik * O + o] = src[i];
}

// ---------------------------------------------------------------------------
// conv3d along D: 32 -> 64 channels, kernel 3, pad 1. One thread per (b,d,p),
// computes all 64 output channels. Writes raw (pre-GN) output as bf16.
// ---------------------------------------------------------------------------
__global__ __launch_bounds__(256) void conv1_kernel(
    const float* __restrict__ x,
    const float* __restrict__ w1T,   // [ci*3+kd][64]
    const float* __restrict__ b1,    // [64]
    __hip_bfloat16* __restrict__ A)  // [B][64][D][HW]
{
    long idx = (long)blockIdx.x * 256 + threadIdx.x;
    if (idx >= NPIX) return;
    int p  = (int)(idx % HWn);
    int bd = (int)(idx / HWn);
    int d  = bd % Dn;
    int b  = bd / Dn;

    float acc[64];
#pragma unroll
    for (int o = 0; o < 64; o++) acc[o] = b1[o];

    for (int kd = 0; kd < 3; kd++) {
        int dd = d + kd - 1;
        if (dd < 0 || dd >= Dn) continue;
        const float* xp = x + (long)b * Cn * DHWn + (long)dd * HWn + p;
        for (int ci = 0; ci < 32; ci++) {
            float v = xp[(long)ci * DHWn];
            const float* wp = w1T + (ci * 3 + kd) * 64;
#pragma unroll
            for (int o = 0; o < 64; o++) acc[o] += wp[o] * v;
        }
    }
    __hip_bfloat16* Ap = A + (long)b * 64 * DHWn + (long)d * HWn + p;
#pragma unroll
    for (int o = 0; o < 64; o++) Ap[(long)o * DHWn] = f2bf(acc[o]);
}

// ---------------------------------------------------------------------------
// GroupNorm stats: per (b,g) slab (contiguous 8*DHW elements of A) compute
// sum and sum-of-squares. grid = (150, 16): 150 chunks of 32768 per slab.
// ---------------------------------------------------------------------------
__global__ __launch_bounds__(256) void stats_kernel(
    const __hip_bfloat16* __restrict__ A, float* __restrict__ gsum, float* __restrict__ gsq)
{
    int slab = blockIdx.y;  // b*8+g
    const __hip_bfloat16* base = A + (long)slab * 8 * DHWn + (long)blockIdx.x * 32768;
    float s = 0.f, q = 0.f;
    for (int i = threadIdx.x; i < 32768; i += 256) {
        float v = bf2f(base[i]);
        s += v;
        q += v * v;
    }
    __shared__ float rs_[256], rq_[256];
    int tid = threadIdx.x;
    rs_[tid] = s; rq_[tid] = q;
    __syncthreads();
    for (int st = 128; st > 0; st >>= 1) {
        if (tid < st) { rs_[tid] += rs_[tid + st]; rq_[tid] += rq_[tid + st]; }
        __syncthreads();
    }
    if (tid == 0) {
        atomicAdd(&gsum[slab], rs_[0]);
        atomicAdd(&gsq[slab],  rq_[0]);
    }
}

// Per-(b,ci) affine: scale = rsqrt(var+eps)*gamma, shift = beta - mu*scale
__global__ __launch_bounds__(128) void finalize_kernel(
    const float* __restrict__ gsum, const float* __restrict__ gsq,
    const float* __restrict__ gn_g, const float* __restrict__ gn_b,
    float* __restrict__ scale, float* __restrict__ shift)
{
    int t = threadIdx.x;
    if (t >= 128) return;
    int b = t >> 6, ci = t & 63, g = ci >> 3;
    float N   = 8.0f * (float)DHWn;
    float mu  = gsum[b * 8 + g] / N;
    float var = gsq[b * 8 + g] / N - mu * mu;
    float rs  = rsqrtf(var + EPS_GN);
    float sc  = rs * gn_g[ci];
    scale[t] = sc;
    shift[t] = gn_b[ci] - mu * sc;
}

// ---------------------------------------------------------------------------
// conv3d along D: 64 -> 32 with fused GroupNorm + LeakyReLU on the input read.
// Writes out = conv2 + x (the "x +" part of enhanced) as fp32.
// ---------------------------------------------------------------------------
__global__ __launch_bounds__(256) void conv2_kernel(
    const __hip_bfloat16* __restrict__ A,
    const float* __restrict__ w2T,   // [ci*3+kd][32]
    const float* __restrict__ b2,    // [32]
    const float* __restrict__ scale, const float* __restrict__ shift,  // [B*64]
    const float* __restrict__ x,
    float* __restrict__ out)
{
    long idx = (long)blockIdx.x * 256 + threadIdx.x;
    if (idx >= NPIX) return;
    int p  = (int)(idx % HWn);
    int bd = (int)(idx / HWn);
    int d  = bd % Dn;
    int b  = bd / Dn;

    float acc[32];
#pragma unroll
    for (int o = 0; o < 32; o++) acc[o] = b2[o];

    const float* scb = scale + b * 64;
    const float* shb = shift + b * 64;

    for (int kd = 0; kd < 3; kd++) {
        int dd = d + kd - 1;
        if (dd < 0 || dd >= Dn) continue;
        const __hip_bfloat16* Ap = A + (long)b * 64 * DHWn + (long)dd * HWn + p;
        for (int ci = 0; ci < 64; ci++) {
            float a  = bf2f(Ap[(long)ci * DHWn]);
            float an = a * scb[ci] + shb[ci];
            an = an >= 0.f ? an : NEG_SLOPE * an;
            const float* wp = w2T + (ci * 3 + kd) * 32;
#pragma unroll
            for (int o = 0; o < 32; o++) acc[o] += wp[o] * an;
        }
    }
    const float* xp = x   + (long)b * Cn * DHWn + (long)d * HWn + p;
    float*       op = out + (long)b * Cn * DHWn + (long)d * HWn + p;
#pragma unroll
    for (int o = 0; o < 32; o++)
        op[(long)o * DHWn] = acc[o] + xp[(long)o * DHWn];
}

// ---------------------------------------------------------------------------
// GRU gates: u = sigmoid(conv([x_d, h], w_u)), rh = sigmoid(conv(..., w_r))*h.
// Both scan directions batched: idx >= GPIX -> backward dir with its own state.
// One thread per pixel, 32+32 accumulators.
// ---------------------------------------------------------------------------
__global__ __launch_bounds__(128) void gates_kernel(
    const float* __restrict__ x, int dfwd, int dbwd,
    const float* __restrict__ h,
    const float* __restrict__ wuT, const float* __restrict__ wrT,  // [(ci*9+k)][32]
    const float* __restrict__ bu,  const float* __restrict__ br,
    float* __restrict__ u, float* __restrict__ rh)
{
    int idx = blockIdx.x * 128 + threadIdx.x;
    if (idx >= 2 * GPIX) return;
    int dir = idx / GPIX;
    int rem = idx - dir * GPIX;
    int b   = rem / HWn;
    int p   = rem - b * HWn;
    int y0  = p / Wn, x0 = p - y0 * Wn;
    int d   = dir ? dbwd : dfwd;

    const float* xb = x + (long)b * Cn * DHWn + (long)d * HWn;
    long sbase = ((long)dir * Bn + b) * Cn * HWn;
    const float* hb = h + sbase;

    float au[32], ar[32];
#pragma unroll
    for (int o = 0; o < 32; o++) { au[o] = bu[o]; ar[o] = br[o]; }

    for (int ky = 0; ky < 3; ky++) {
        int yy = y0 + ky - 1;
        if (yy < 0 || yy >= Hn) continue;
        for (int kx = 0; kx < 3; kx++) {
            int xx = x0 + kx - 1;
            if (xx < 0 || xx >= Wn) continue;
            int off = yy * Wn + xx;
            int k = ky * 3 + kx;
            for (int ci = 0; ci < 32; ci++) {
                float v = xb[(long)ci * DHWn + off];
                const float* wup = wuT + (ci * 9 + k) * 32;
                const float* wrp = wrT + (ci * 9 + k) * 32;
#pragma unroll
                for (int o = 0; o < 32; o++) { au[o] += wup[o] * v; ar[o] += wrp[o] * v; }
            }
            for (int ci = 0; ci < 32; ci++) {
                float v = hb[ci * HWn + off];
                const float* wup = wuT + ((32 + ci) * 9 + k) * 32;
                const float* wrp = wrT + ((32 + ci) * 9 + k) * 32;
#pragma unroll
                for (int o = 0; o < 32; o++) { au[o] += wup[o] * v; ar[o] += wrp[o] * v; }
            }
        }
    }
    float* ub  = u  + sbase;
    float* rhb = rh + sbase;
#pragma unroll
    for (int o = 0; o < 32; o++) {
        float uu = 1.f / (1.f + __expf(-au[o]));
        float rr = 1.f / (1.f + __expf(-ar[o]));
        ub[o * HWn + p]  = uu;
        rhb[o * HWn + p] = rr * hb[o * HWn + p];
    }
}

// ---------------------------------------------------------------------------
// GRU candidate + state update: cand = tanh(conv([x_d, rh], w_o)),
// h_new = (1-u)h + u*cand; h <- h_new; out[b,:,d,:] += h_new (fp32 RMW).
// ---------------------------------------------------------------------------
__global__ __launch_bounds__(128) void cand_kernel(
    const float* __restrict__ x, int dfwd, int dbwd,
    const float* __restrict__ woT, const float* __restrict__ bo,
    const float* __restrict__ u, const float* __restrict__ rh,
    float* __restrict__ h, float* __restrict__ out)
{
    int idx = blockIdx.x * 128 + threadIdx.x;
    if (idx >= 2 * GPIX) return;
    int dir = idx / GPIX;
    int rem = idx - dir * GPIX;
    int b   = rem / HWn;
    int p   = rem - b * HWn;
    int y0  = p / Wn, x0 = p - y0 * Wn;
    int d   = dir ? dbwd : dfwd;

    const float* xb = x + (long)b * Cn * DHWn + (long)d * HWn;
    long sbase = ((long)dir * Bn + b) * Cn * HWn;
    const float* rhb = rh + sbase;

    float acc[32];
#pragma unroll
    for (int o = 0; o < 32; o++) acc[o] = bo[o];

    for (int ky = 0; ky < 3; ky++) {
        int yy = y0 + ky - 1;
        if (yy < 0 || yy >= Hn) continue;
        for (int kx = 0; kx < 3; kx++) {
            int xx = x0 + kx - 1;
            if (xx < 0 || xx >= Wn) continue;
            int off = yy * Wn + xx;
            int k = ky * 3 + kx;
            for (int ci = 0; ci < 32; ci++) {
                float v = xb[(long)ci * DHWn + off];
                const float* wp = woT + (ci * 9 + k) * 32;
#pragma unroll
                for (int o = 0; o < 32; o++) acc[o] += wp[o] * v;
            }
            for (int ci = 0; ci < 32; ci++) {
                float v = rhb[ci * HWn + off];
                const float* wp = woT + ((32 + ci) * 9 + k) * 32;
#pragma unroll
                for (int o = 0; o < 32; o++) acc[o] += wp[o] * v;
            }
        }
    }
    const float* ub = u + sbase;
    float*       hb = h + sbase;
#pragma unroll
    for (int o = 0; o < 32; o++) {
        float e  = __expf(2.f * acc[o]);
        float c  = 1.f - 2.f / (e + 1.f);           // tanh
        float uu = ub[o * HWn + p];
        float hp = hb[o * HWn + p];
        float hn = (1.f - uu) * hp + uu * c;
        hb[o * HWn + p] = hn;
        long oi = ((long)b * Cn + o) * DHWn + (long)d * HWn + p;
        out[oi] += hn;
    }
}

// ---------------------------------------------------------------------------
extern "C" void kernel_launch(void* const* d_in, const int* in_sizes, int n_in,
                              void* d_out, int out_size, void* d_ws, size_t ws_size,
                              hipStream_t stream)
{
    const float* x    = (const float*)d_in[0];
    const float* w_f1 = (const float*)d_in[1];
    const float* b_f1 = (const float*)d_in[2];
    const float* gn_g = (const float*)d_in[3];
    const float* gn_b = (const float*)d_in[4];
    const float* w_f2 = (const float*)d_in[5];
    const float* b_f2 = (const float*)d_in[6];
    const float* w_u  = (const float*)d_in[7];
    const float* b_u  = (const float*)d_in[8];
    const float* w_r  = (const float*)d_in[9];
    const float* b_r  = (const float*)d_in[10];
    const float* w_o  = (const float*)d_in[11];
    const float* b_o  = (const float*)d_in[12];
    float* out = (float*)d_out;

    // ---- workspace layout (fp32 region, then bf16 A buffer) ----
    float* wf = (float*)d_ws;
    long off = 0;
    float* w1T  = wf + off; off += 64 * 96;
    float* w2T  = wf + off; off += 32 * 192;
    float* wuT  = wf + off; off += 32 * 576;
    float* wrT  = wf + off; off += 32 * 576;
    float* woT  = wf + off; off += 32 * 576;
    float* gsum = wf + off; off += 16;
    float* gsq  = wf + off; off += 16;   // contiguous with gsum for one memset
    float* scal = wf + off; off += 128;
    float* shft = wf + off; off += 128;
    const long STATE = 2L * Bn * Cn * HWn;  // [dir][b][c][hw]
    float* hbuf  = wf + off; off += STATE;
    float* ubuf  = wf + off; off += STATE;
    float* rhbuf = wf + off; off += STATE;

    long fbytes = ((off * 4) + 255) & ~255L;
    __hip_bfloat16* A = (__hip_bfloat16*)((char*)d_ws + fbytes);
    long need = fbytes + 2L * Bn * 64 * DHWn;  // + A bytes (bf16)
    if ((long)ws_size < need) return;  // workspace too small: cannot run

    // ---- weight transpose (biases/gamma/beta used directly) ----
    auto tr = [&](const float* s, float* dst, int O, int IK) {
        int n = O * IK;
        wtrans_kernel<<<(n + 255) / 256, 256, 0, stream>>>(s, dst, O, IK);
    };
    tr(w_f1, w1T, 64, 96);
    tr(w_f2, w2T, 32, 192);
    tr(w_u,  wuT, 32, 576);
    tr(w_r,  wrT, 32, 576);
    tr(w_o,  woT, 32, 576);

    // ---- slice_flow path ----
    conv1_kernel<<<(int)(NPIX / 256), 256, 0, stream>>>(x, w1T, b_f1, A);
    hipMemsetAsync(gsum, 0, 32 * sizeof(float), stream);
    stats_kernel<<<dim3(150, 16), 256, 0, stream>>>(A, gsum, gsq);
    finalize_kernel<<<1, 128, 0, stream>>>(gsum, gsq, gn_g, gn_b, scal, shft);
    conv2_kernel<<<(int)(NPIX / 256), 256, 0, stream>>>(A, w2T, b_f2, scal, shft, x, out);

    // ---- bidirectional GRU scan (both directions batched per step) ----
    hipMemsetAsync(hbuf, 0, STATE * sizeof(float), stream);
    for (int s = 0; s < Dn; s++) {
        int dfwd = s, dbwd = Dn - 1 - s;
        gates_kernel<<<(2 * GPIX) / 128, 128, 0, stream>>>(
            x, dfwd, dbwd, hbuf, wuT, wrT, b_u, b_r, ubuf, rhbuf);
        cand_kernel<<<(2 * GPIX) / 128, 128, 0, stream>>>(
            x, dfwd, dbwd, woT, b_o, ubuf, rhbuf, hbuf, out);
    }
}

// Round 3
// 2309.287 us; speedup vs baseline: 4.5739x; 4.5739x over previous
//
#include <hip/hip_runtime.h>
#include <hip/hip_bf16.h>
#include <stdint.h>

#define EPS_GN 1e-5f
#define NEG_SLOPE 0.2f

static constexpr int  Bn   = 2;
static constexpr int  Cn   = 32;
static constexpr int  Dn   = 24;
static constexpr int  Hn   = 160;
static constexpr int  Wn   = 160;
static constexpr int  HWn  = Hn * Wn;              // 25600
static constexpr long DHWn = (long)Dn * HWn;       // 614400
static constexpr long NPIX = (long)Bn * Dn * HWn;  // 1228800

using frag8  = __attribute__((ext_vector_type(8)))  short;  // 8 bf16 (4 VGPRs)
using accf16 = __attribute__((ext_vector_type(16))) float;  // 32x32 C/D frag

__device__ __forceinline__ float bf2f(__hip_bfloat16 v) { return __bfloat162float(v); }
__device__ __forceinline__ __hip_bfloat16 f2bf(float v) { return __float2bfloat16(v); }
__device__ __forceinline__ float sigm(float v) { return 1.f / (1.f + __expf(-v)); }
__device__ __forceinline__ float tanh_(float v) {
    float e = __expf(2.f * v);
    return 1.f - 2.f / (e + 1.f);
}

// ---------------------------------------------------------------------------
// Transpose fp32 weight [O][IK] -> [IK][O] (for the two conv3d kernels).
// ---------------------------------------------------------------------------
__global__ __launch_bounds__(256) void wtrans_kernel(
    const float* __restrict__ src, float* __restrict__ dst, int O, int IK)
{
    int i = blockIdx.x * 256 + threadIdx.x;
    if (i >= O * IK) return;
    int o = i / IK, ik = i - o * IK;
    dst[ik * O + o] = src[i];
}

// ---------------------------------------------------------------------------
// Pack GRU conv weight [32][64][3][3] fp32 into MFMA B-fragment lane order:
// dst[tap][kb][lane][j] = w[o=lane&31][ci=kb*16+(lane>>5)*8+j][tap], bf16.
// ---------------------------------------------------------------------------
__global__ __launch_bounds__(256) void bpack_kernel(
    const float* __restrict__ w, __hip_bfloat16* __restrict__ dst)
{
    int t = blockIdx.x * 256 + threadIdx.x;
    if (t >= 9 * 4 * 64 * 8) return;
    int j    = t & 7;
    int lane = (t >> 3) & 63;
    int kb   = (t >> 9) & 3;
    int tap  = t >> 11;
    int ci   = kb * 16 + (lane >> 5) * 8 + j;
    int o    = lane & 31;
    dst[t] = f2bf(w[(o * 64 + ci) * 9 + tap]);
}

// ---------------------------------------------------------------------------
// x [B][C][D][HW] fp32 -> xhwc [B][D][HW][32] bf16 via LDS transpose tile.
// ---------------------------------------------------------------------------
__global__ __launch_bounds__(256) void tohwc_kernel(
    const float* __restrict__ x, __hip_bfloat16* __restrict__ xhwc)
{
    __shared__ float tile[32][65];
    int bd = blockIdx.y;            // b*Dn+d
    int b  = bd / Dn, d = bd % Dn;
    int p0 = blockIdx.x * 64;
    const float* xb = x + (long)b * Cn * DHWn + (long)d * HWn + p0;
    for (int e = threadIdx.x; e < 2048; e += 256) {
        int c = e >> 6, p = e & 63;
        tile[c][p] = xb[(long)c * DHWn + p];
    }
    __syncthreads();
    __hip_bfloat16* ob = xhwc + ((long)bd * HWn + p0) * 32;
    for (int e = threadIdx.x; e < 2048; e += 256) {
        int p = e >> 5, c = e & 31;
        ob[p * 32 + c] = f2bf(tile[c][p]);
    }
}

// ---------------------------------------------------------------------------
// conv3d along D: 32 -> 64, k=3, pad 1. Writes pre-GN output as bf16.
// ---------------------------------------------------------------------------
__global__ __launch_bounds__(256) void conv1_kernel(
    const float* __restrict__ x,
    const float* __restrict__ w1T,   // [ci*3+kd][64]
    const float* __restrict__ b1,
    __hip_bfloat16* __restrict__ A)  // [B][64][D][HW]
{
    long idx = (long)blockIdx.x * 256 + threadIdx.x;
    if (idx >= NPIX) return;
    int p  = (int)(idx % HWn);
    int bd = (int)(idx / HWn);
    int d  = bd % Dn;
    int b  = bd / Dn;

    float acc[64];
#pragma unroll
    for (int o = 0; o < 64; o++) acc[o] = b1[o];

    for (int kd = 0; kd < 3; kd++) {
        int dd = d + kd - 1;
        if (dd < 0 || dd >= Dn) continue;
        const float* xp = x + (long)b * Cn * DHWn + (long)dd * HWn + p;
        for (int ci = 0; ci < 32; ci++) {
            float v = xp[(long)ci * DHWn];
            const float* wp = w1T + (ci * 3 + kd) * 64;
#pragma unroll
            for (int o = 0; o < 64; o++) acc[o] += wp[o] * v;
        }
    }
    __hip_bfloat16* Ap = A + (long)b * 64 * DHWn + (long)d * HWn + p;
#pragma unroll
    for (int o = 0; o < 64; o++) Ap[(long)o * DHWn] = f2bf(acc[o]);
}

// ---------------------------------------------------------------------------
// GroupNorm stats over slabs of A.
// ---------------------------------------------------------------------------
__global__ __launch_bounds__(256) void stats_kernel(
    const __hip_bfloat16* __restrict__ A, float* __restrict__ gsum, float* __restrict__ gsq)
{
    int slab = blockIdx.y;  // b*8+g
    const __hip_bfloat16* base = A + (long)slab * 8 * DHWn + (long)blockIdx.x * 32768;
    float s = 0.f, q = 0.f;
    for (int i = threadIdx.x; i < 32768; i += 256) {
        float v = bf2f(base[i]);
        s += v;
        q += v * v;
    }
    __shared__ float rs_[256], rq_[256];
    int tid = threadIdx.x;
    rs_[tid] = s; rq_[tid] = q;
    __syncthreads();
    for (int st = 128; st > 0; st >>= 1) {
        if (tid < st) { rs_[tid] += rs_[tid + st]; rq_[tid] += rq_[tid + st]; }
        __syncthreads();
    }
    if (tid == 0) {
        atomicAdd(&gsum[slab], rs_[0]);
        atomicAdd(&gsq[slab],  rq_[0]);
    }
}

__global__ __launch_bounds__(128) void finalize_kernel(
    const float* __restrict__ gsum, const float* __restrict__ gsq,
    const float* __restrict__ gn_g, const float* __restrict__ gn_b,
    float* __restrict__ scale, float* __restrict__ shift)
{
    int t = threadIdx.x;
    if (t >= 128) return;
    int b = t >> 6, ci = t & 63, g = ci >> 3;
    float N   = 8.0f * (float)DHWn;
    float mu  = gsum[b * 8 + g] / N;
    float var = gsq[b * 8 + g] / N - mu * mu;
    float rs  = rsqrtf(var + EPS_GN);
    float sc  = rs * gn_g[ci];
    scale[t] = sc;
    shift[t] = gn_b[ci] - mu * sc;
}

// ---------------------------------------------------------------------------
// conv3d along D: 64 -> 32 with fused GN + LeakyReLU. out = conv + x (fp32).
// ---------------------------------------------------------------------------
__global__ __launch_bounds__(256) void conv2_kernel(
    const __hip_bfloat16* __restrict__ A,
    const float* __restrict__ w2T,   // [ci*3+kd][32]
    const float* __restrict__ b2,
    const float* __restrict__ scale, const float* __restrict__ shift,
    const float* __restrict__ x,
    float* __restrict__ out)
{
    long idx = (long)blockIdx.x * 256 + threadIdx.x;
    if (idx >= NPIX) return;
    int p  = (int)(idx % HWn);
    int bd = (int)(idx / HWn);
    int d  = bd % Dn;
    int b  = bd / Dn;

    float acc[32];
#pragma unroll
    for (int o = 0; o < 32; o++) acc[o] = b2[o];

    const float* scb = scale + b * 64;
    const float* shb = shift + b * 64;

    for (int kd = 0; kd < 3; kd++) {
        int dd = d + kd - 1;
        if (dd < 0 || dd >= Dn) continue;
        const __hip_bfloat16* Ap = A + (long)b * 64 * DHWn + (long)dd * HWn + p;
        for (int ci = 0; ci < 64; ci++) {
            float a  = bf2f(Ap[(long)ci * DHWn]);
            float an = a * scb[ci] + shb[ci];
            an = an >= 0.f ? an : NEG_SLOPE * an;
            const float* wp = w2T + (ci * 3 + kd) * 32;
#pragma unroll
            for (int o = 0; o < 32; o++) acc[o] += wp[o] * an;
        }
    }
    const float* xp = x   + (long)b * Cn * DHWn + (long)d * HWn + p;
    float*       op = out + (long)b * Cn * DHWn + (long)d * HWn + p;
#pragma unroll
    for (int o = 0; o < 32; o++)
        op[(long)o * DHWn] = acc[o] + xp[(long)o * DHWn];
}

// ---------------------------------------------------------------------------
// GRU gates via MFMA. Block = 4 waves; wave handles 2 M-tiles of 32 pixels.
// K = 9 taps x 64 ch (x: kb 0-1, h: kb 2-3). N = 32, two gates (u, r) share A.
// Epilogue: u -> frag-order fp32 buffer, r*h -> HWC bf16.
// ---------------------------------------------------------------------------
__global__ __launch_bounds__(256) void gru_gates_mfma(
    const __hip_bfloat16* __restrict__ xhwc,  // [B][D][HW][32]
    int dfwd, int dbwd,
    const __hip_bfloat16* __restrict__ hbf,   // [2][B][HW][32]
    const __hip_bfloat16* __restrict__ Bu,    // [9][4][64][8]
    const __hip_bfloat16* __restrict__ Br,
    const float* __restrict__ bu, const float* __restrict__ br,
    float* __restrict__ ufrag,                // [3200][1024]
    __hip_bfloat16* __restrict__ rhbf)        // [2][B][HW][32]
{
    int db   = blockIdx.y;          // dir*2 + b
    int dir  = db >> 1, b = db & 1;
    int d    = dir ? dbwd : dfwd;
    int wave = threadIdx.x >> 6;
    int lane = threadIdx.x & 63;
    int ml   = lane & 31;
    int kh   = lane >> 5;

    const __hip_bfloat16* xb = xhwc + ((long)b * Dn + d) * HWn * 32;
    const __hip_bfloat16* hb = hbf  + (long)db * HWn * 32;

    int tile0 = blockIdx.x * 8 + wave * 2;    // 0..798
    int tb[2]   = { tile0 * 32, tile0 * 32 + 32 };
    int py0[2]  = { tb[0] / Wn, tb[1] / Wn };
    int px0[2]  = { tb[0] % Wn, tb[1] % Wn };

    accf16 au[2], ar[2];
#pragma unroll
    for (int t = 0; t < 2; t++)
#pragma unroll
        for (int i = 0; i < 16; i++) { au[t][i] = 0.f; ar[t][i] = 0.f; }

    for (int tap = 0; tap < 9; tap++) {
        int dy = tap / 3 - 1, dx = tap % 3 - 1;
        long poff[2]; bool ok[2];
#pragma unroll
        for (int t = 0; t < 2; t++) {
            int yy = py0[t] + dy;
            int xx = px0[t] + ml + dx;
            ok[t]   = ((unsigned)yy < (unsigned)Hn) & ((unsigned)xx < (unsigned)Wn);
            poff[t] = ((long)(yy * Wn + xx)) * 32;
        }
#pragma unroll
        for (int kb = 0; kb < 4; kb++) {
            frag8 bu_f = *(const frag8*)(Bu + ((tap * 4 + kb) * 64 + lane) * 8);
            frag8 br_f = *(const frag8*)(Br + ((tap * 4 + kb) * 64 + lane) * 8);
            int ch = kb * 16 + kh * 8;
            const __hip_bfloat16* bsel = (kb < 2) ? (xb + ch) : (hb + (ch - 32));
#pragma unroll
            for (int t = 0; t < 2; t++) {
                frag8 a = {};
                if (ok[t]) a = *(const frag8*)(bsel + poff[t]);
                au[t] = __builtin_amdgcn_mfma_f32_32x32x16_bf16(a, bu_f, au[t], 0, 0, 0);
                ar[t] = __builtin_amdgcn_mfma_f32_32x32x16_bf16(a, br_f, ar[t], 0, 0, 0);
            }
        }
    }

    int ch = ml;
    float bias_u = bu[ch], bias_r = br[ch];
#pragma unroll
    for (int t = 0; t < 2; t++) {
        int pb = tb[t];
        float* uf = ufrag + ((long)db * 800 + tile0 + t) * 1024 + lane * 16;
        __hip_bfloat16* rhb = rhbf + (long)db * HWn * 32;
#pragma unroll
        for (int i = 0; i < 16; i++) {
            int row = (i & 3) + 8 * (i >> 2) + 4 * kh;
            int pix = pb + row;
            float hp = bf2f(hb[(long)pix * 32 + ch]);
            float uu = sigm(au[t][i] + bias_u);
            float rr = sigm(ar[t][i] + bias_r);
            uf[i] = uu;
            rhb[(long)pix * 32 + ch] = f2bf(rr * hp);
        }
    }
}

// ---------------------------------------------------------------------------
// GRU candidate + update via MFMA. A source: x (kb 0-1), r*h (kb 2-3).
// Epilogue: c=tanh(.), h_new=(1-u)h+u*c; h (bf16 HWC) updated; out += h_new.
// ---------------------------------------------------------------------------
__global__ __launch_bounds__(256) void gru_cand_mfma(
    const __hip_bfloat16* __restrict__ xhwc,
    int dfwd, int dbwd,
    const __hip_bfloat16* __restrict__ rhbf,
    const __hip_bfloat16* __restrict__ Bo,
    const float* __restrict__ bo,
    const float* __restrict__ ufrag,
    __hip_bfloat16* __restrict__ hbf,
    float* __restrict__ out)
{
    int db   = blockIdx.y;
    int dir  = db >> 1, b = db & 1;
    int d    = dir ? dbwd : dfwd;
    int wave = threadIdx.x >> 6;
    int lane = threadIdx.x & 63;
    int ml   = lane & 31;
    int kh   = lane >> 5;

    const __hip_bfloat16* xb  = xhwc + ((long)b * Dn + d) * HWn * 32;
    const __hip_bfloat16* rhb = rhbf + (long)db * HWn * 32;
    __hip_bfloat16*       hb  = hbf  + (long)db * HWn * 32;

    int tile0 = blockIdx.x * 8 + wave * 2;
    int tb[2]   = { tile0 * 32, tile0 * 32 + 32 };
    int py0[2]  = { tb[0] / Wn, tb[1] / Wn };
    int px0[2]  = { tb[0] % Wn, tb[1] % Wn };

    accf16 ao[2];
#pragma unroll
    for (int t = 0; t < 2; t++)
#pragma unroll
        for (int i = 0; i < 16; i++) ao[t][i] = 0.f;

    for (int tap = 0; tap < 9; tap++) {
        int dy = tap / 3 - 1, dx = tap % 3 - 1;
        long poff[2]; bool ok[2];
#pragma unroll
        for (int t = 0; t < 2; t++) {
            int yy = py0[t] + dy;
            int xx = px0[t] + ml + dx;
            ok[t]   = ((unsigned)yy < (unsigned)Hn) & ((unsigned)xx < (unsigned)Wn);
            poff[t] = ((long)(yy * Wn + xx)) * 32;
        }
#pragma unroll
        for (int kb = 0; kb < 4; kb++) {
            frag8 bo_f = *(const frag8*)(Bo + ((tap * 4 + kb) * 64 + lane) * 8);
            int ch = kb * 16 + kh * 8;
            const __hip_bfloat16* bsel = (kb < 2) ? (xb + ch) : (rhb + (ch - 32));
#pragma unroll
            for (int t = 0; t < 2; t++) {
                frag8 a = {};
                if (ok[t]) a = *(const frag8*)(bsel + poff[t]);
                ao[t] = __builtin_amdgcn_mfma_f32_32x32x16_bf16(a, bo_f, ao[t], 0, 0, 0);
            }
        }
    }

    int ch = ml;
    float bias_o = bo[ch];
#pragma unroll
    for (int t = 0; t < 2; t++) {
        int pb = tb[t];
        const float* uf = ufrag + ((long)db * 800 + tile0 + t) * 1024 + lane * 16;
        float* ob = out + ((long)b * Cn + ch) * DHWn + (long)d * HWn;
#pragma unroll
        for (int i = 0; i < 16; i++) {
            int row = (i & 3) + 8 * (i >> 2) + 4 * kh;
            int pix = pb + row;
            float c  = tanh_(ao[t][i] + bias_o);
            float uu = uf[i];
            float hp = bf2f(hb[(long)pix * 32 + ch]);
            float hn = (1.f - uu) * hp + uu * c;
            hb[(long)pix * 32 + ch] = f2bf(hn);
            ob[pix] += hn;
        }
    }
}

// ---------------------------------------------------------------------------
extern "C" void kernel_launch(void* const* d_in, const int* in_sizes, int n_in,
                              void* d_out, int out_size, void* d_ws, size_t ws_size,
                              hipStream_t stream)
{
    const float* x    = (const float*)d_in[0];
    const float* w_f1 = (const float*)d_in[1];
    const float* b_f1 = (const float*)d_in[2];
    const float* gn_g = (const float*)d_in[3];
    const float* gn_b = (const float*)d_in[4];
    const float* w_f2 = (const float*)d_in[5];
    const float* b_f2 = (const float*)d_in[6];
    const float* w_u  = (const float*)d_in[7];
    const float* b_u  = (const float*)d_in[8];
    const float* w_r  = (const float*)d_in[9];
    const float* b_r  = (const float*)d_in[10];
    const float* w_o  = (const float*)d_in[11];
    const float* b_o  = (const float*)d_in[12];
    float* out = (float*)d_out;

    // ---- workspace layout ----
    char* ws = (char*)d_ws;
    float* w1T  = (float*)ws;          // 64*96
    float* w2T  = w1T + 64 * 96;       // 32*192
    float* gsum = w2T + 32 * 192;      // 16
    float* gsq  = gsum + 16;           // 16 (contiguous for one memset)
    float* scal = gsq + 16;            // 128
    float* shft = scal + 128;          // 128
    __hip_bfloat16* Bu = (__hip_bfloat16*)(shft + 128);  // 18432 each
    __hip_bfloat16* Br = Bu + 18432;
    __hip_bfloat16* Bo = Br + 18432;
    char* big = (char*)(Bo + 18432);
    big = (char*)(((uintptr_t)big + 255) & ~(uintptr_t)255);

    // Phase A (conv path): A occupies [0, 157.3MB) of big.
    __hip_bfloat16* A = (__hip_bfloat16*)big;
    // Phase B (GRU): overlapping sub-buffers (A is dead after conv2).
    __hip_bfloat16* xhwc  = (__hip_bfloat16*)big;                 // 78,643,200 B
    __hip_bfloat16* hbf   = (__hip_bfloat16*)(big + 78643200L);   //  6,553,600 B
    __hip_bfloat16* rhbf  = (__hip_bfloat16*)(big + 85196800L);   //  6,553,600 B
    float*          ufrag = (float*)        (big + 91750400L);    // 13,107,200 B

    size_t need = (size_t)(big - ws) + 157286400UL;
    if (ws_size < need) return;  // workspace too small

    // ---- weight transforms ----
    auto tr = [&](const float* s, float* dst, int O, int IK) {
        int n = O * IK;
        wtrans_kernel<<<(n + 255) / 256, 256, 0, stream>>>(s, dst, O, IK);
    };
    tr(w_f1, w1T, 64, 96);
    tr(w_f2, w2T, 32, 192);
    bpack_kernel<<<72, 256, 0, stream>>>(w_u, Bu);
    bpack_kernel<<<72, 256, 0, stream>>>(w_r, Br);
    bpack_kernel<<<72, 256, 0, stream>>>(w_o, Bo);

    // ---- slice_flow path (uses A region) ----
    conv1_kernel<<<(int)(NPIX / 256), 256, 0, stream>>>(x, w1T, b_f1, A);
    hipMemsetAsync(gsum, 0, 32 * sizeof(float), stream);
    stats_kernel<<<dim3(150, 16), 256, 0, stream>>>(A, gsum, gsq);
    finalize_kernel<<<1, 128, 0, stream>>>(gsum, gsq, gn_g, gn_b, scal, shft);
    conv2_kernel<<<(int)(NPIX / 256), 256, 0, stream>>>(A, w2T, b_f2, scal, shft, x, out);

    // ---- GRU phase: build xhwc (overwrites A region), zero h ----
    tohwc_kernel<<<dim3(400, Bn * Dn), 256, 0, stream>>>(x, xhwc);
    hipMemsetAsync(hbf, 0, 6553600, stream);

    for (int s = 0; s < Dn; s++) {
        int dfwd = s, dbwd = Dn - 1 - s;
        gru_gates_mfma<<<dim3(100, 4), 256, 0, stream>>>(
            xhwc, dfwd, dbwd, hbf, Bu, Br, b_u, b_r, ufrag, rhbf);
        gru_cand_mfma<<<dim3(100, 4), 256, 0, stream>>>(
            xhwc, dfwd, dbwd, rhbf, Bo, b_o, ufrag, hbf, out);
    }
}